// Round 1
// baseline (135.938 us; speedup 1.0000x reference)
//
#include <hip/hip_runtime.h>

using u16    = unsigned short;
using f32x4  = __attribute__((ext_vector_type(4))) float;
using bf16x8 = __attribute__((ext_vector_type(8))) __bf16;

#define E_CNT 400000
#define G_CNT 1024
#define NROWS 401024   // E+G = 3133*128 exactly
#define NBLK  3133

// ws layout (bytes)
#define WS_NRBF   0u          // [65536][128] bf16 = 16777216
#define WS_GFBF   16777216u   // [1024][384] bf16  =   786432
#define WS_WT     17563648u   // [128][544] bf16   =   139264  (col-major-of-K, zero-padded K 516..543)
#define WS_NME    17702912u   // [160] bf16        =      320  (no_more_edges, zero-padded)
#define WS_BIAS   17703232u   // [128] f32         =      512

__device__ __forceinline__ u16 f2bf(float f) {
  unsigned u = __builtin_bit_cast(unsigned, f);
  return (u16)((u + 0x7fffu + ((u >> 16) & 1u)) >> 16);  // RNE
}

__device__ __forceinline__ void gload16(const void* g, void* l) {
  __builtin_amdgcn_global_load_lds((const __attribute__((address_space(1))) void*)g,
                                   (__attribute__((address_space(3))) void*)l, 16, 0, 0);
}

// ---------- precompute kernels ----------

// node_representations f32 -> bf16, 2,097,152 float4 = 8192*256
__global__ __launch_bounds__(256) void k_conv_nr(const float4* __restrict__ in,
                                                 u16* __restrict__ out) {
  int i = blockIdx.x * 256 + threadIdx.x;
  float4 v = in[i];
  unsigned lo = (unsigned)f2bf(v.x) | ((unsigned)f2bf(v.y) << 16);
  unsigned hi = (unsigned)f2bf(v.z) | ((unsigned)f2bf(v.w) << 16);
  reinterpret_cast<uint2*>(out)[i] = make_uint2(lo, hi);
}

// graph_and_focus -> bf16 [1024][384]
__global__ __launch_bounds__(128) void k_gf(const float* __restrict__ imr,
                                            const float* __restrict__ pgr,
                                            const float* __restrict__ nr,
                                            const int* __restrict__ focus,
                                            u16* __restrict__ gfbf) {
  int g = blockIdx.x, t = threadIdx.x;
  int fi = focus[g];
  u16* row = gfbf + (size_t)g * 384;
  row[t]       = f2bf(imr[(size_t)g * 128 + t]);
  row[128 + t] = f2bf(pgr[(size_t)g * 128 + t]);
  row[256 + t] = f2bf(nr[(size_t)fi * 128 + t]);
}

// W_T[col][k]: col<64 -> scorer_W1[k][col], col>=64 -> type_W1[k][col-64]; k>=516 -> 0
__global__ __launch_bounds__(256) void k_wt(const float* __restrict__ sW1,
                                            const float* __restrict__ tW1,
                                            u16* __restrict__ wt) {
  int idx = blockIdx.x * 256 + threadIdx.x;
  if (idx >= 128 * 544) return;
  int col = idx / 544;
  int k = idx - col * 544;
  float v = 0.f;
  if (k < 516) v = (col < 64) ? sW1[(size_t)k * 64 + col] : tW1[(size_t)k * 64 + (col - 64)];
  wt[idx] = f2bf(v);
}

// no_more_edges -> bf16 (padded to 160), bias[128] = [scorer_b1 | type_b1]
__global__ __launch_bounds__(256) void k_misc(const float* __restrict__ nme,
                                              const float* __restrict__ sb1,
                                              const float* __restrict__ tb1,
                                              u16* __restrict__ nmebf,
                                              float* __restrict__ bias) {
  int t = threadIdx.x;
  if (t < 160) nmebf[t] = (t < 132) ? f2bf(nme[t]) : (u16)0;
  if (t < 64) bias[t] = sb1[t];
  else if (t < 128) bias[t] = tb1[t - 64];
}

// ---------- fused gather-GEMM + dual epilogue ----------
// Tile: BM=128 rows x BN=128 hidden, BK=32, 17 K-steps (K padded 516->544).
// 4 waves 2x2; wave (wr,wc) owns 64x64. Chunks 0..11: GF gather; 12..15: NR gather
// (or NME for stop blocks); 16: computed tail [dist_emb, f1..f3, 0...].
__global__ __launch_bounds__(256) void fused_mlp(
    const u16* __restrict__ NRbf, const u16* __restrict__ GFbf,
    const u16* __restrict__ WT, const u16* __restrict__ NMEbf,
    const float* __restrict__ bias128,
    const int* __restrict__ tgt, const int* __restrict__ n2g,
    const float* __restrict__ feats, const float* __restrict__ dtab,
    const float* __restrict__ sW2, const float* __restrict__ sb2,
    const float* __restrict__ tW2, const float* __restrict__ tb2,
    float* __restrict__ out0, float* __restrict__ out1) {
  __shared__ u16 As[128 * 32];  // [row][k] 64B rows
  __shared__ u16 Bs[128 * 32];  // [col][k] 64B rows

  const int tid = threadIdx.x;
  const int l = tid & 63, w = tid >> 6;
  const int row0 = blockIdx.x * 128;
  const bool edge = (row0 < E_CNT);  // blocks are homogeneous (400000 = 3125*128)

  // ---- staging addressing: wave w, issue j in {0,1} covers 16 rows/cols each ----
  const int rr = l >> 2;      // row within 16-row stripe
  const int so = (l & 3) * 16;  // 16B slot within 64B row
  const char *pA0, *pA1, *pA0n, *pA1n;
  {
    int m0 = row0 + w * 16 + rr, m1 = m0 + 64;
    if (edge) {
      int t0 = tgt[m0], t1 = tgt[m1];
      int g0 = n2g[t0], g1 = n2g[t1];
      pA0 = (const char*)GFbf + (size_t)g0 * 768;
      pA1 = (const char*)GFbf + (size_t)g1 * 768;
      pA0n = (const char*)NRbf + (size_t)t0 * 256;
      pA1n = (const char*)NRbf + (size_t)t1 * 256;
    } else {
      pA0 = (const char*)GFbf + (size_t)(m0 - E_CNT) * 768;
      pA1 = (const char*)GFbf + (size_t)(m1 - E_CNT) * 768;
      pA0n = (const char*)NMEbf;
      pA1n = (const char*)NMEbf;
    }
  }
  const char* pB0 = (const char*)WT + (size_t)(w * 16 + rr) * 1088 + so;
  const char* pB1 = pB0 + (size_t)64 * 1088;
  char* ldsA0 = (char*)As + w * 1024;
  char* ldsA1 = (char*)As + (4 + w) * 1024;
  char* ldsB0 = (char*)Bs + w * 1024;
  char* ldsB1 = (char*)Bs + (4 + w) * 1024;

  const int wr = w >> 1, wc = w & 1;
  const int lr = l & 15, lg = l >> 4;

  f32x4 acc[4][4];
#pragma unroll
  for (int i = 0; i < 4; ++i)
#pragma unroll
    for (int j = 0; j < 4; ++j) acc[i][j] = (f32x4){0.f, 0.f, 0.f, 0.f};

  for (int c = 0; c < 17; ++c) {
    __syncthreads();  // previous iter's ds_reads done before overwrite
    if (c < 12) {
      gload16(pA0 + c * 64 + so, ldsA0);
      gload16(pA1 + c * 64 + so, ldsA1);
    } else if (c < 16) {
      gload16(pA0n + (c - 12) * 64 + so, ldsA0);
      gload16(pA1n + (c - 12) * 64 + so, ldsA1);
    } else {
      if (tid < 128) {  // computed tail chunk: [dist_emb, f1, f2, f3, 0 x28]
        int m = row0 + tid;
        u16 v0, v1, v2, v3;
        if (edge) {
          const float4 f = *(const float4*)(feats + (size_t)m * 4);
          int td = (int)fminf(f.x, 9.0f);
          v0 = f2bf(dtab[td]); v1 = f2bf(f.y); v2 = f2bf(f.z); v3 = f2bf(f.w);
        } else {
          v0 = NMEbf[128]; v1 = NMEbf[129]; v2 = NMEbf[130]; v3 = NMEbf[131];
        }
        u16* dst = As + tid * 32;
        dst[0] = v0; dst[1] = v1; dst[2] = v2; dst[3] = v3;
#pragma unroll
        for (int k = 4; k < 32; ++k) dst[k] = 0;
      }
    }
    gload16(pB0 + c * 64, ldsB0);  // WT is zero-padded so chunk 16 is uniform
    gload16(pB1 + c * 64, ldsB1);
    __syncthreads();  // compiler drains vmcnt+lgkmcnt before s_barrier

    bf16x8 aF[4], bF[4];
#pragma unroll
    for (int fm = 0; fm < 4; ++fm)
      aF[fm] = *(const bf16x8*)(As + (wr * 64 + fm * 16 + lr) * 32 + lg * 8);
#pragma unroll
    for (int fn = 0; fn < 4; ++fn)
      bF[fn] = *(const bf16x8*)(Bs + (wc * 64 + fn * 16 + lr) * 32 + lg * 8);
#pragma unroll
    for (int fm = 0; fm < 4; ++fm)
#pragma unroll
      for (int fn = 0; fn < 4; ++fn)
        acc[fm][fn] = __builtin_amdgcn_mfma_f32_16x16x32_bf16(aF[fm], bF[fn], acc[fm][fn], 0, 0, 0);
  }

  // ---- epilogue. C layout: col = lane&15 (+fn*16+wc*64), row = lg*4+reg (+fm*16+wr*64)
  if (wc == 0) {  // scorer head: logit = sum_h relu(acc+b)*W2[h] + b2
    float w2v[4], bb[4];
#pragma unroll
    for (int fn = 0; fn < 4; ++fn) {
      int hh = fn * 16 + lr;
      w2v[fn] = sW2[hh];
      bb[fn] = bias128[hh];
    }
    float b2 = sb2[0];
#pragma unroll
    for (int fm = 0; fm < 4; ++fm) {
      float p[4] = {0.f, 0.f, 0.f, 0.f};
#pragma unroll
      for (int fn = 0; fn < 4; ++fn)
#pragma unroll
        for (int rg = 0; rg < 4; ++rg)
          p[rg] += fmaxf(acc[fm][fn][rg] + bb[fn], 0.f) * w2v[fn];
#pragma unroll
      for (int rg = 0; rg < 4; ++rg)
#pragma unroll
        for (int m = 1; m < 16; m <<= 1) p[rg] += __shfl_xor(p[rg], m, 64);
      if (lr == 0) {
        int rbase = row0 + wr * 64 + fm * 16 + lg * 4;
#pragma unroll
        for (int rg = 0; rg < 4; ++rg) out0[rbase + rg] = p[rg] + b2;
      }
    }
  } else if (edge) {  // type head (edge rows only)
    float bb[4], tw0[4], tw1[4], tw2v[4];
#pragma unroll
    for (int fn = 0; fn < 4; ++fn) {
      int hh = fn * 16 + lr;
      bb[fn] = bias128[64 + hh];
      tw0[fn] = tW2[hh * 3 + 0];
      tw1[fn] = tW2[hh * 3 + 1];
      tw2v[fn] = tW2[hh * 3 + 2];
    }
    float tb0 = tb2[0], tb1 = tb2[1], tb2s = tb2[2];
#pragma unroll
    for (int fm = 0; fm < 4; ++fm) {
      float p0[4] = {0.f, 0.f, 0.f, 0.f}, p1[4] = {0.f, 0.f, 0.f, 0.f}, p2[4] = {0.f, 0.f, 0.f, 0.f};
#pragma unroll
      for (int fn = 0; fn < 4; ++fn)
#pragma unroll
        for (int rg = 0; rg < 4; ++rg) {
          float h = fmaxf(acc[fm][fn][rg] + bb[fn], 0.f);
          p0[rg] += h * tw0[fn];
          p1[rg] += h * tw1[fn];
          p2[rg] += h * tw2v[fn];
        }
#pragma unroll
      for (int rg = 0; rg < 4; ++rg)
#pragma unroll
        for (int m = 1; m < 16; m <<= 1) {
          p0[rg] += __shfl_xor(p0[rg], m, 64);
          p1[rg] += __shfl_xor(p1[rg], m, 64);
          p2[rg] += __shfl_xor(p2[rg], m, 64);
        }
      if (lr == 0) {
        int rbase = row0 + wr * 64 + fm * 16 + lg * 4;
#pragma unroll
        for (int rg = 0; rg < 4; ++rg) {
          size_t o = (size_t)(rbase + rg) * 3;
          out1[o + 0] = p0[rg] + tb0;
          out1[o + 1] = p1[rg] + tb1;
          out1[o + 2] = p2[rg] + tb2s;
        }
      }
    }
  }
}

extern "C" void kernel_launch(void* const* d_in, const int* in_sizes, int n_in,
                              void* d_out, int out_size, void* d_ws, size_t ws_size,
                              hipStream_t stream) {
  const float* imr   = (const float*)d_in[0];
  const float* pgr   = (const float*)d_in[1];
  const float* nr    = (const float*)d_in[2];
  const int*   focus = (const int*)d_in[3];
  const int*   n2g   = (const int*)d_in[4];
  const int*   tgt   = (const int*)d_in[5];
  const float* feats = (const float*)d_in[6];
  const float* dtab  = (const float*)d_in[8];
  const float* nme   = (const float*)d_in[9];
  const float* sW1   = (const float*)d_in[10];
  const float* sb1   = (const float*)d_in[11];
  const float* sW2   = (const float*)d_in[12];
  const float* sb2   = (const float*)d_in[13];
  const float* tW1   = (const float*)d_in[14];
  const float* tb1   = (const float*)d_in[15];
  const float* tW2   = (const float*)d_in[16];
  const float* tb2   = (const float*)d_in[17];

  char* ws = (char*)d_ws;
  u16*   NRbf  = (u16*)(ws + WS_NRBF);
  u16*   GFbf  = (u16*)(ws + WS_GFBF);
  u16*   WT    = (u16*)(ws + WS_WT);
  u16*   NMEbf = (u16*)(ws + WS_NME);
  float* bias  = (float*)(ws + WS_BIAS);

  float* out0 = (float*)d_out;          // [401024]
  float* out1 = out0 + NROWS;           // [400000*3]

  k_conv_nr<<<8192, 256, 0, stream>>>((const float4*)nr, NRbf);
  k_gf<<<1024, 128, 0, stream>>>(imr, pgr, nr, focus, GFbf);
  k_wt<<<272, 256, 0, stream>>>(sW1, tW1, WT);
  k_misc<<<1, 256, 0, stream>>>(nme, sb1, tb1, NMEbf, bias);
  fused_mlp<<<NBLK, 256, 0, stream>>>(NRbf, GFbf, WT, NMEbf, bias, tgt, n2g, feats,
                                      dtab, sW2, sb2, tW2, tb2, out0, out1);
}

// Round 3
// 96.715 us; speedup vs baseline: 1.4055x; 1.4055x over previous
//
#include <hip/hip_runtime.h>

using u16    = unsigned short;
using f32x4  = __attribute__((ext_vector_type(4))) float;
using bf16x8 = __attribute__((ext_vector_type(8))) __bf16;

#define E_CNT 400000
#define G_CNT 1024
#define NROWS 401024   // E+G = 3133*128 exactly
#define NBLK  3133

// ws layout (bytes)
#define WS_NRBF   0u          // [65536][128] bf16 = 16777216
#define WS_GFBF   16777216u   // [1024][384] bf16  =   786432
#define WS_WT     17563648u   // [128][544] bf16   =   139264  (W columns as rows, K zero-padded 516..543)
#define WS_NME    17702912u   // [160] bf16        =      320  (no_more_edges, zero-padded)
#define WS_BIAS   17703232u   // [128] f32         =      512

__device__ __forceinline__ u16 f2bf(float f) {
  unsigned u = __builtin_bit_cast(unsigned, f);
  return (u16)((u + 0x7fffu + ((u >> 16) & 1u)) >> 16);  // RNE
}

__device__ __forceinline__ void gload16(const void* g, void* l) {
  __builtin_amdgcn_global_load_lds((const __attribute__((address_space(1))) void*)g,
                                   (__attribute__((address_space(3))) void*)l, 16, 0, 0);
}

// ---------- precompute kernels ----------

__global__ __launch_bounds__(256) void k_conv_nr(const float4* __restrict__ in,
                                                 u16* __restrict__ out) {
  int i = blockIdx.x * 256 + threadIdx.x;
  float4 v = in[i];
  unsigned lo = (unsigned)f2bf(v.x) | ((unsigned)f2bf(v.y) << 16);
  unsigned hi = (unsigned)f2bf(v.z) | ((unsigned)f2bf(v.w) << 16);
  reinterpret_cast<uint2*>(out)[i] = make_uint2(lo, hi);
}

__global__ __launch_bounds__(128) void k_gf(const float* __restrict__ imr,
                                            const float* __restrict__ pgr,
                                            const float* __restrict__ nr,
                                            const int* __restrict__ focus,
                                            u16* __restrict__ gfbf) {
  int g = blockIdx.x, t = threadIdx.x;
  int fi = focus[g];
  u16* row = gfbf + (size_t)g * 384;
  row[t]       = f2bf(imr[(size_t)g * 128 + t]);
  row[128 + t] = f2bf(pgr[(size_t)g * 128 + t]);
  row[256 + t] = f2bf(nr[(size_t)fi * 128 + t]);
}

__global__ __launch_bounds__(256) void k_wt(const float* __restrict__ sW1,
                                            const float* __restrict__ tW1,
                                            u16* __restrict__ wt) {
  int idx = blockIdx.x * 256 + threadIdx.x;
  if (idx >= 128 * 544) return;
  int col = idx / 544;
  int k = idx - col * 544;
  float v = 0.f;
  if (k < 516) v = (col < 64) ? sW1[(size_t)k * 64 + col] : tW1[(size_t)k * 64 + (col - 64)];
  wt[idx] = f2bf(v);
}

__global__ __launch_bounds__(256) void k_misc(const float* __restrict__ nme,
                                              const float* __restrict__ sb1,
                                              const float* __restrict__ tb1,
                                              u16* __restrict__ nmebf,
                                              float* __restrict__ bias) {
  int t = threadIdx.x;
  if (t < 160) nmebf[t] = (t < 132) ? f2bf(nme[t]) : (u16)0;
  if (t < 64) bias[t] = sb1[t];
  else if (t < 128) bias[t] = tb1[t - 64];
}

// ---------- fused gather-GEMM + dual epilogue ----------
// BM=128 x BN=128, BK=32, K padded 544 (17 chunks). Depth-2 ring-3 pipeline,
// ONE barrier per step. Wait = vmcnt(4) [stage(c+1) stays in flight] +
// lgkmcnt(0) [REQUIRED: drains this wave's ds_reads before it signals the
// barrier — MFMAs are register-only and may sink past the barrier, so MFMA
// consumption does NOT imply lgkm drain; without this, stage(c+2)'s DMA
// overwrites LDS lines with reads still outstanding -> round-2 corruption].
// LDS rows 64B; swizzle class q=(row>>1)&3 at 16B slots: bank-group =
// 4*(row&1)+slot, so 8 consecutive lanes cover all 8 groups -> conflict-free
// ds_read_b128. Applied as pre-swizzled global source + swizzled read addr;
// gload dest stays linear (rule 21).
__global__ __launch_bounds__(256, 3) void fused_mlp(
    const u16* __restrict__ NRbf, const u16* __restrict__ GFbf,
    const u16* __restrict__ WT, const u16* __restrict__ NMEbf,
    const float* __restrict__ bias128,
    const int* __restrict__ tgt, const int* __restrict__ n2g,
    const float* __restrict__ feats, const float* __restrict__ dtab,
    const float* __restrict__ sW2, const float* __restrict__ sb2,
    const float* __restrict__ tW2, const float* __restrict__ tb2,
    float* __restrict__ out0, float* __restrict__ out1) {
  __shared__ uint4 ldsbuf[3072];  // 3 rings x (A 8KB + B 8KB) = 49152 B
  char* const lds = (char*)ldsbuf;

  const int tid = threadIdx.x;
  const int l = tid & 63, w = tid >> 6;
  const int row0 = blockIdx.x * 128;
  const bool edge = (row0 < E_CNT);  // blocks homogeneous (400000 = 3125*128)

  // staging: wave w covers rows w*16..+15 (issue0) and +64 (issue1); lane l:
  // row rr=l>>2, dest slot l&3, SOURCE slot (l&3)^q, q=(rr>>1)&3=(l>>3)&3
  const int rr = l >> 2;
  const int so = (((l & 3) ^ ((l >> 3) & 3)) << 4);
  const char *pA0, *pA1, *pAn0, *pAn1;
  {
    int m0 = row0 + w * 16 + rr;
    if (edge) {
      int t0 = tgt[m0], t1 = tgt[m0 + 64];
      int g0 = n2g[t0], g1 = n2g[t1];
      pA0  = (const char*)GFbf + (size_t)g0 * 768 + so;
      pA1  = (const char*)GFbf + (size_t)g1 * 768 + so;
      pAn0 = (const char*)NRbf + (size_t)t0 * 256 + so;
      pAn1 = (const char*)NRbf + (size_t)t1 * 256 + so;
    } else {
      pA0  = (const char*)GFbf + (size_t)(m0 - E_CNT) * 768 + so;
      pA1  = pA0 + 64 * 768;
      pAn0 = (const char*)NMEbf + so;  // uniform: every stop row gets NME
      pAn1 = pAn0;
    }
  }
  const char* pB0 = (const char*)WT + (size_t)(w * 16 + rr) * 1088 + so;
  const char* pB1 = pB0 + (size_t)64 * 1088;

  auto stage = [&](int c2, int roff) {
    char* la = lds + roff + w * 1024;
    char* lb = la + 8192;
    if (c2 < 12) {
      gload16(pA0 + c2 * 64, la);
      gload16(pA1 + c2 * 64, la + 4096);
    } else {
      gload16(pAn0 + (c2 - 12) * 64, la);
      gload16(pAn1 + (c2 - 12) * 64, la + 4096);
    }
    gload16(pB0 + c2 * 64, lb);
    gload16(pB1 + c2 * 64, lb + 4096);
  };

  const int wr = w >> 1, wc = w & 1;
  const int lr = l & 15, lg = l >> 4;
  const int rdsw = ((lg ^ ((lr >> 1) & 3)) << 4);  // read-side swizzled slot

  f32x4 acc[4][4];
#pragma unroll
  for (int i = 0; i < 4; ++i)
#pragma unroll
    for (int j = 0; j < 4; ++j) acc[i][j] = (f32x4){0.f, 0.f, 0.f, 0.f};

  stage(0, 0);
  stage(1, 16384);
  int rc = 0, rs = 32768;

  for (int c = 0; c < 16; ++c) {
    // own ds_reads drained (lgkm) + own stage(c) landed (vmcnt<=4) before barrier
    if (c < 15) asm volatile("s_waitcnt vmcnt(4) lgkmcnt(0)" ::: "memory");
    else        asm volatile("s_waitcnt vmcnt(2) lgkmcnt(0)" ::: "memory");
    __builtin_amdgcn_s_barrier();
    asm volatile("" ::: "memory");

    if (c < 14) {
      stage(c + 2, rs);
    } else if (c == 14) {  // chunk 16: B only (A tail built via ds_write later)
      char* lb = lds + rs + w * 1024 + 8192;
      gload16(pB0 + 16 * 64, lb);
      gload16(pB1 + 16 * 64, lb + 4096);
    }

    bf16x8 aF[4], bF[4];
    const char* ba = lds + rc;
    const char* bb = ba + 8192;
#pragma unroll
    for (int fm = 0; fm < 4; ++fm)
      aF[fm] = *(const bf16x8*)(ba + (wr * 64 + fm * 16 + lr) * 64 + rdsw);
#pragma unroll
    for (int fn = 0; fn < 4; ++fn)
      bF[fn] = *(const bf16x8*)(bb + (wc * 64 + fn * 16 + lr) * 64 + rdsw);
#pragma unroll
    for (int fm = 0; fm < 4; ++fm)
#pragma unroll
      for (int fn = 0; fn < 4; ++fn)
        acc[fm][fn] = __builtin_amdgcn_mfma_f32_16x16x32_bf16(aF[fm], bF[fn], acc[fm][fn], 0, 0, 0);

    rc += 16384; if (rc == 49152) rc = 0;
    rs += 16384; if (rs == 49152) rs = 0;
  }

  // ---- tail step: chunk 16 (k 512..543) in ring rc (== 16384 here) ----
  asm volatile("s_waitcnt vmcnt(0)" ::: "memory");  // chunk-16 B staged
  if (tid < 128) {  // build A tail rows: [dist_emb, f1, f2, f3, 0 x28], swizzled
    int m = row0 + tid;
    u16 v0, v1, v2, v3;
    if (edge) {
      const float4 f = *(const float4*)(feats + (size_t)m * 4);
      int td = (int)fminf(f.x, 9.0f);
      v0 = f2bf(dtab[td]); v1 = f2bf(f.y); v2 = f2bf(f.z); v3 = f2bf(f.w);
    } else {
      v0 = NMEbf[128]; v1 = NMEbf[129]; v2 = NMEbf[130]; v3 = NMEbf[131];
    }
    uint4 val, zero;
    val.x = (unsigned)v0 | ((unsigned)v1 << 16);
    val.y = (unsigned)v2 | ((unsigned)v3 << 16);
    val.z = 0u; val.w = 0u;
    zero.x = zero.y = zero.z = zero.w = 0u;
    int q = (tid >> 1) & 3;
    char* dst = lds + rc + tid * 64;
#pragma unroll
    for (int s = 0; s < 4; ++s) *(uint4*)(dst + s * 16) = (s == q) ? val : zero;
  }
  asm volatile("s_waitcnt lgkmcnt(0)" ::: "memory");
  __builtin_amdgcn_s_barrier();
  asm volatile("" ::: "memory");
  {
    bf16x8 aF[4], bF[4];
    const char* ba = lds + rc;
    const char* bb = ba + 8192;
#pragma unroll
    for (int fm = 0; fm < 4; ++fm)
      aF[fm] = *(const bf16x8*)(ba + (wr * 64 + fm * 16 + lr) * 64 + rdsw);
#pragma unroll
    for (int fn = 0; fn < 4; ++fn)
      bF[fn] = *(const bf16x8*)(bb + (wc * 64 + fn * 16 + lr) * 64 + rdsw);
#pragma unroll
    for (int fm = 0; fm < 4; ++fm)
#pragma unroll
      for (int fn = 0; fn < 4; ++fn)
        acc[fm][fn] = __builtin_amdgcn_mfma_f32_16x16x32_bf16(aF[fm], bF[fn], acc[fm][fn], 0, 0, 0);
  }

  // ---- epilogue. C layout: col = lane&15 (+fn*16+wc*64), row = lg*4+reg (+fm*16+wr*64)
  if (wc == 0) {  // scorer head
    float w2v[4], bb[4];
#pragma unroll
    for (int fn = 0; fn < 4; ++fn) {
      int hh = fn * 16 + lr;
      w2v[fn] = sW2[hh];
      bb[fn] = bias128[hh];
    }
    float b2 = sb2[0];
#pragma unroll
    for (int fm = 0; fm < 4; ++fm) {
      float p[4] = {0.f, 0.f, 0.f, 0.f};
#pragma unroll
      for (int fn = 0; fn < 4; ++fn)
#pragma unroll
        for (int rg = 0; rg < 4; ++rg)
          p[rg] += fmaxf(acc[fm][fn][rg] + bb[fn], 0.f) * w2v[fn];
#pragma unroll
      for (int rg = 0; rg < 4; ++rg)
#pragma unroll
        for (int m = 1; m < 16; m <<= 1) p[rg] += __shfl_xor(p[rg], m, 64);
      if (lr == 0) {
        int rbase = row0 + wr * 64 + fm * 16 + lg * 4;
#pragma unroll
        for (int rg = 0; rg < 4; ++rg) out0[rbase + rg] = p[rg] + b2;
      }
    }
  } else if (edge) {  // type head (edge rows only)
    float bb[4], tw0[4], tw1[4], tw2v[4];
#pragma unroll
    for (int fn = 0; fn < 4; ++fn) {
      int hh = fn * 16 + lr;
      bb[fn] = bias128[64 + hh];
      tw0[fn] = tW2[hh * 3 + 0];
      tw1[fn] = tW2[hh * 3 + 1];
      tw2v[fn] = tW2[hh * 3 + 2];
    }
    float tb0 = tb2[0], tb1 = tb2[1], tb2s = tb2[2];
#pragma unroll
    for (int fm = 0; fm < 4; ++fm) {
      float p0[4] = {0.f, 0.f, 0.f, 0.f}, p1[4] = {0.f, 0.f, 0.f, 0.f}, p2[4] = {0.f, 0.f, 0.f, 0.f};
#pragma unroll
      for (int fn = 0; fn < 4; ++fn)
#pragma unroll
        for (int rg = 0; rg < 4; ++rg) {
          float h = fmaxf(acc[fm][fn][rg] + bb[fn], 0.f);
          p0[rg] += h * tw0[fn];
          p1[rg] += h * tw1[fn];
          p2[rg] += h * tw2v[fn];
        }
#pragma unroll
      for (int rg = 0; rg < 4; ++rg)
#pragma unroll
        for (int m = 1; m < 16; m <<= 1) {
          p0[rg] += __shfl_xor(p0[rg], m, 64);
          p1[rg] += __shfl_xor(p1[rg], m, 64);
          p2[rg] += __shfl_xor(p2[rg], m, 64);
        }
      if (lr == 0) {
        int rbase = row0 + wr * 64 + fm * 16 + lg * 4;
#pragma unroll
        for (int rg = 0; rg < 4; ++rg) {
          size_t o = (size_t)(rbase + rg) * 3;
          out1[o + 0] = p0[rg] + tb0;
          out1[o + 1] = p1[rg] + tb1;
          out1[o + 2] = p2[rg] + tb2s;
        }
      }
    }
  }
}

extern "C" void kernel_launch(void* const* d_in, const int* in_sizes, int n_in,
                              void* d_out, int out_size, void* d_ws, size_t ws_size,
                              hipStream_t stream) {
  const float* imr   = (const float*)d_in[0];
  const float* pgr   = (const float*)d_in[1];
  const float* nr    = (const float*)d_in[2];
  const int*   focus = (const int*)d_in[3];
  const int*   n2g   = (const int*)d_in[4];
  const int*   tgt   = (const int*)d_in[5];
  const float* feats = (const float*)d_in[6];
  const float* dtab  = (const float*)d_in[8];
  const float* nme   = (const float*)d_in[9];
  const float* sW1   = (const float*)d_in[10];
  const float* sb1   = (const float*)d_in[11];
  const float* sW2   = (const float*)d_in[12];
  const float* sb2   = (const float*)d_in[13];
  const float* tW1   = (const float*)d_in[14];
  const float* tb1   = (const float*)d_in[15];
  const float* tW2   = (const float*)d_in[16];
  const float* tb2   = (const float*)d_in[17];

  char* ws = (char*)d_ws;
  u16*   NRbf  = (u16*)(ws + WS_NRBF);
  u16*   GFbf  = (u16*)(ws + WS_GFBF);
  u16*   WT    = (u16*)(ws + WS_WT);
  u16*   NMEbf = (u16*)(ws + WS_NME);
  float* bias  = (float*)(ws + WS_BIAS);

  float* out0 = (float*)d_out;          // [401024]
  float* out1 = out0 + NROWS;           // [400000*3]

  k_conv_nr<<<8192, 256, 0, stream>>>((const float4*)nr, NRbf);
  k_gf<<<1024, 128, 0, stream>>>(imr, pgr, nr, focus, GFbf);
  k_wt<<<272, 256, 0, stream>>>(sW1, tW1, WT);
  k_misc<<<1, 256, 0, stream>>>(nme, sb1, tb1, NMEbf, bias);
  fused_mlp<<<NBLK, 256, 0, stream>>>(NRbf, GFbf, WT, NMEbf, bias, tgt, n2g, feats,
                                      dtab, sW2, sb2, tW2, tb2, out0, out1);
}